// Round 1
// baseline (936.200 us; speedup 1.0000x reference)
//
#include <hip/hip_runtime.h>

// ---------------------------------------------------------------------------
// PredictModelWithCLasses: fused per-protein MLP on MI355X (gfx950).
//
// Math: out[b,p] = w3_p . lrelu( W2_p^T . lrelu( Wcat_p^T . [pe(b,p)|spot(b)] + c_p ) + b2_p ) + b3_p
// where Wcat_p = [proj_W @ TW_top ; TW_bot] @ W1_p   (1056 x 136), fused since
// there is NO activation between trans_dim and W1.
//
// Pipeline (all on `stream`):
//   k_g / k_gcopy : G = [proj_W@TW_top ; TW_bot]  (1056x544 f32)
//   k_d, k_c      : fused bias  c_p = (proj_b@TW_top + trans_b)@W1_p + b1_p
//   k_pack_w1     : W1 -> MFMA-B-fragment bf16 pack (for k_pk3)
//   k_pack_w2     : W2 -> MFMA-B-fragment bf16 pack (K padded 136->160)
//   k_pk3         : Wcat_p = G @ W1_p (grouped MFMA GEMM), written B-fragment packed
//   k_main        : the fused 3-stage kernel, one WG per (protein, 128 rows)
// ---------------------------------------------------------------------------

typedef short bf16x8 __attribute__((ext_vector_type(8)));   // 8 bf16 (raw bits)
typedef unsigned short u16;
typedef u16 u16x8 __attribute__((ext_vector_type(8)));
typedef float f32x4 __attribute__((ext_vector_type(4)));

typedef const void __attribute__((address_space(1)))* gas_p;
typedef void __attribute__((address_space(3)))* las_p;

__device__ __forceinline__ void gl_lds16(const void* g, void* l) {
  // async global->LDS, 16B per lane; LDS dest = uniform base + lane*16
  __builtin_amdgcn_global_load_lds((gas_p)g, (las_p)l, 16, 0, 0);
}

__device__ __forceinline__ u16 f2bf(float f) {  // f32 -> bf16 RTNE
  union { float f; unsigned u; } x; x.f = f;
  return (u16)((x.u + 0x7FFFu + ((x.u >> 16) & 1u)) >> 16);
}

// ---------------- tiny precompute kernels ----------------------------------

// G top: G[r][c] = sum_k proj_W[r][k] * trans_W[k][c]   (r<512)
__global__ void k_g(const float* __restrict__ projW, const float* __restrict__ transW,
                    float* __restrict__ G) {
  const int rb = blockIdx.x;          // 0..31 -> rows rb*16..rb*16+15
  const int tid = threadIdx.x;
  for (int c = tid; c < 544; c += 256) {
    float a[16];
#pragma unroll
    for (int r = 0; r < 16; ++r) a[r] = 0.f;
    for (int k = 0; k < 512; ++k) {
      const float tw = transW[k * 544 + c];
#pragma unroll
      for (int r = 0; r < 16; ++r) a[r] += projW[(rb * 16 + r) * 512 + k] * tw;
    }
#pragma unroll
    for (int r = 0; r < 16; ++r) G[(rb * 16 + r) * 544 + c] = a[r];
  }
}

// G bottom: copy trans_W rows 512..1055
__global__ void k_gcopy(const float* __restrict__ transW, float* __restrict__ G) {
  const int idx = blockIdx.x * 256 + threadIdx.x;   // float4 units, 73984 total
  if (idx >= 73984) return;
  ((float4*)G)[69632 + idx] = ((const float4*)transW)[69632 + idx];
}

// d[c] = proj_b @ TW_top + trans_b
__global__ void k_d(const float* __restrict__ projb, const float* __restrict__ transW,
                    const float* __restrict__ transb, float* __restrict__ dvec) {
  const int c = blockIdx.x * 256 + threadIdx.x;
  if (c >= 544) return;
  float s = transb[c];
  for (int k = 0; k < 512; ++k) s += projb[k] * transW[k * 544 + c];
  dvec[c] = s;
}

// c_p[col] = d @ W1_p + b1_p   (padded to 144, pad = 0)
__global__ void k_c(const float* __restrict__ dvec, const float* __restrict__ W1,
                    const float* __restrict__ b1, float* __restrict__ cvec) {
  const int idx = blockIdx.x * 256 + threadIdx.x;
  if (idx >= 64 * 144) return;
  const int p = idx / 144, col = idx % 144;
  float s = 0.f;
  if (col < 136) {
    s = b1[p * 136 + col];
    for (int k = 0; k < 544; ++k) s += dvec[k] * W1[((size_t)p * 544 + k) * 136 + col];
  }
  cvec[idx] = s;
}

// Pack W1 into MFMA-B-fragment order, bf16:
// dest ushort off = ((p*17+kt)*9 + n)*512 + (kblk*16+col)*8 + j ; value W1[p][kt*32+kblk*8+j][n*16+col] (0 if col>=136)
__global__ void k_pack_w1(const float* __restrict__ W1, u16* __restrict__ W1pk) {
  const int uid = blockIdx.x * 256 + threadIdx.x;    // < 64*17*9*64 = 626688
  const int unit = uid & 63;
  const int rest = uid >> 6;
  const int n = rest % 9;
  const int tile = rest / 9;        // p*17 + kt
  const int kt = tile % 17;
  const int pp = tile / 17;
  const int kb = unit >> 4, cl = unit & 15;
  const int colg = n * 16 + cl;
  u16x8 v;
#pragma unroll
  for (int j = 0; j < 8; ++j) {
    const int k = kt * 32 + kb * 8 + j;              // < 544
    v[j] = (colg < 136) ? f2bf(W1[((size_t)pp * 544 + k) * 136 + colg]) : (u16)0;
  }
  *(u16x8*)(W1pk + (size_t)uid * 8) = v;
}

// Pack W2 (K padded 136->160): dest off = ((p*5+kt)*17 + n)*512 + (kblk*16+col)*8 + j
__global__ void k_pack_w2(const float* __restrict__ W2, u16* __restrict__ W2pk) {
  const int uid = blockIdx.x * 256 + threadIdx.x;    // < 64*5*17*64 = 348160
  const int unit = uid & 63;
  const int rest = uid >> 6;
  const int n = rest % 17;
  const int tile = rest / 17;       // p*5 + kt
  const int kt = tile % 5;
  const int pp = tile / 5;
  const int kb = unit >> 4, cl = unit & 15;
  const int colg = n * 16 + cl;                      // < 272
  u16x8 v;
#pragma unroll
  for (int j = 0; j < 8; ++j) {
    const int k = kt * 32 + kb * 8 + j;              // < 160
    v[j] = (k < 136) ? f2bf(W2[((size_t)pp * 136 + k) * 272 + colg]) : (u16)0;
  }
  *(u16x8*)(W2pk + (size_t)uid * 8) = v;
}

// ---------------- grouped GEMM: Wcat_p = G @ W1_p ---------------------------
// M=1056 (9 tiles of 128, guarded), K=544 (17 steps), N=144. Output written in
// the main kernel's B-fragment packed layout.
__global__ __launch_bounds__(256, 2)
void k_pk3(const float* __restrict__ G, const u16* __restrict__ W1pk,
           u16* __restrict__ Wpk) {
  __shared__ char smem[34816];
  char* const Ab0 = smem;            // 2 x 8192
  char* const Bb0 = smem + 16384;    // 2 x 9216
  const int t = threadIdx.x, lane = t & 63, w = t >> 6;
  const int l15 = lane & 15, kq = lane >> 4;
  const int mt = blockIdx.x, p = blockIdx.y;
  const int sr = t >> 1, sh = t & 1, sf = (sr >> 1) & 3;
  const int gr = mt * 128 + sr;
  const bool aval = (gr < 1056);

  const f32x4 fz = {0.f, 0.f, 0.f, 0.f};
  f32x4 acc[2][9];
#pragma unroll
  for (int m = 0; m < 2; ++m)
#pragma unroll
    for (int n = 0; n < 9; ++n) acc[m][n] = fz;

  const u16* wsrc = W1pk + (size_t)p * (17 * 4608);

  float4 pv[4];
  auto preloadA = [&](int kt) {
    if (aval) {
      const float* s = G + (size_t)gr * 544 + kt * 32 + sh * 16;
#pragma unroll
      for (int j = 0; j < 4; ++j) pv[j] = *(const float4*)(s + j * 4);
    } else {
      const float4 z4 = {0.f, 0.f, 0.f, 0.f};
#pragma unroll
      for (int j = 0; j < 4; ++j) pv[j] = z4;
    }
  };
  auto writeA = [&](int buf) {
    u16x8 v0, v1;
    v0[0] = f2bf(pv[0].x); v0[1] = f2bf(pv[0].y); v0[2] = f2bf(pv[0].z); v0[3] = f2bf(pv[0].w);
    v0[4] = f2bf(pv[1].x); v0[5] = f2bf(pv[1].y); v0[6] = f2bf(pv[1].z); v0[7] = f2bf(pv[1].w);
    v1[0] = f2bf(pv[2].x); v1[1] = f2bf(pv[2].y); v1[2] = f2bf(pv[2].z); v1[3] = f2bf(pv[2].w);
    v1[4] = f2bf(pv[3].x); v1[5] = f2bf(pv[3].y); v1[6] = f2bf(pv[3].z); v1[7] = f2bf(pv[3].w);
    char* dst = Ab0 + buf * 8192 + sr * 64;
    *(u16x8*)(dst + ((((sh << 1)) ^ sf) << 4)) = v0;
    *(u16x8*)(dst + ((((sh << 1) | 1) ^ sf) << 4)) = v1;
  };
  auto stageB = [&](int kt, int buf) {
    const u16* src = wsrc + kt * 4608;
    char* dst = Bb0 + buf * 9216;
    for (int i = w; i < 9; i += 4) gl_lds16(src + i * 512 + lane * 8, dst + i * 1024);
  };
  auto compute = [&](int buf) {
    const char* A = Ab0 + buf * 8192;
    const char* Bt = Bb0 + buf * 9216;
    bf16x8 a[2];
#pragma unroll
    for (int m = 0; m < 2; ++m) {
      const int row = w * 32 + m * 16 + l15;
      a[m] = *(const bf16x8*)(A + row * 64 + ((kq ^ ((row >> 1) & 3)) << 4));
    }
#pragma unroll
    for (int n = 0; n < 9; ++n) {
      bf16x8 b = *(const bf16x8*)(Bt + n * 1024 + lane * 16);
      acc[0][n] = __builtin_amdgcn_mfma_f32_16x16x32_bf16(a[0], b, acc[0][n], 0, 0, 0);
      acc[1][n] = __builtin_amdgcn_mfma_f32_16x16x32_bf16(a[1], b, acc[1][n], 0, 0, 0);
    }
  };

  preloadA(0); stageB(0, 0); writeA(0);
  for (int kt = 0; kt < 17; ++kt) {
    __syncthreads();
    const int buf = kt & 1;
    if (kt + 1 < 17) { preloadA(kt + 1); stageB(kt + 1, buf ^ 1); }
    compute(buf);
    if (kt + 1 < 17) writeA(buf ^ 1);
  }

  // epilogue: scatter into Wpk fragment layout (row = k index of main GEMM)
#pragma unroll
  for (int m = 0; m < 2; ++m)
#pragma unroll
    for (int n = 0; n < 9; ++n)
#pragma unroll
      for (int i = 0; i < 4; ++i) {
        const int row = mt * 128 + w * 32 + m * 16 + (kq << 2) + i;
        if (row < 1056) {
          const int ktw = row >> 5, kk = row & 31;
          const size_t off = (size_t)(p * 33 + ktw) * 4608 + n * 512 +
                             ((kk >> 3) * 16 + l15) * 8 + (kk & 7);
          Wpk[off] = f2bf(acc[m][n][i]);
        }
      }
}

// ---------------- fused main kernel -----------------------------------------
__global__ __launch_bounds__(256, 2)
void k_main(const float* __restrict__ cell, const float* __restrict__ cond,
            const float* __restrict__ pe,
            const u16* __restrict__ Wpk, const u16* __restrict__ W2pk,
            const float* __restrict__ cvec, const float* __restrict__ b2,
            const float* __restrict__ W3, const float* __restrict__ b3,
            float* __restrict__ out) {
  __shared__ char smem[58368];
  char* const Ab0 = smem;            // stage1 A dbuf: 2 x 8192
  char* const Bb0 = smem + 16384;    // stage1 B dbuf: 2 x 9216
  char* const h1  = smem + 17408;    // 128 x 320B (overlaps stage1 bufs; used after)
  char* const B2  = smem;            // stage2 B: 17408B (overlaps dead stage1 bufs)

  const int t = threadIdx.x, lane = t & 63, w = t >> 6;
  const int l15 = lane & 15, kq = lane >> 4;
  const int p = blockIdx.y;
  const int b0 = blockIdx.x * 128;
  const int sr = t >> 1, sh = t & 1, sf = (sr >> 1) & 3;
  const long gr = b0 + sr;

  const f32x4 fz = {0.f, 0.f, 0.f, 0.f};
  f32x4 acc[2][9];
#pragma unroll
  for (int m = 0; m < 2; ++m)
#pragma unroll
    for (int n = 0; n < 9; ++n) acc[m][n] = fz;

  const u16* wsrc = Wpk + (size_t)p * (33 * 4608);

  float4 pv[4];
  auto preloadA = [&](int kt) {
    const float* s;
    if (kt < 16)      s = pe + ((gr * 64 + p) << 9) + kt * 32 + sh * 16;
    else if (kt < 32) s = cell + (gr << 9) + (kt - 16) * 32 + sh * 16;
    else              s = cond + (gr << 5) + sh * 16;
#pragma unroll
    for (int j = 0; j < 4; ++j) pv[j] = *(const float4*)(s + j * 4);
  };
  auto writeA = [&](int buf) {
    u16x8 v0, v1;
    v0[0] = f2bf(pv[0].x); v0[1] = f2bf(pv[0].y); v0[2] = f2bf(pv[0].z); v0[3] = f2bf(pv[0].w);
    v0[4] = f2bf(pv[1].x); v0[5] = f2bf(pv[1].y); v0[6] = f2bf(pv[1].z); v0[7] = f2bf(pv[1].w);
    v1[0] = f2bf(pv[2].x); v1[1] = f2bf(pv[2].y); v1[2] = f2bf(pv[2].z); v1[3] = f2bf(pv[2].w);
    v1[4] = f2bf(pv[3].x); v1[5] = f2bf(pv[3].y); v1[6] = f2bf(pv[3].z); v1[7] = f2bf(pv[3].w);
    char* dst = Ab0 + buf * 8192 + sr * 64;
    *(u16x8*)(dst + ((((sh << 1)) ^ sf) << 4)) = v0;
    *(u16x8*)(dst + ((((sh << 1) | 1) ^ sf) << 4)) = v1;
  };
  auto stageB = [&](int kt, int buf) {
    const u16* src = wsrc + kt * 4608;
    char* dst = Bb0 + buf * 9216;
    for (int i = w; i < 9; i += 4) gl_lds16(src + i * 512 + lane * 8, dst + i * 1024);
  };
  auto compute1 = [&](int buf) {
    const char* A = Ab0 + buf * 8192;
    const char* Bt = Bb0 + buf * 9216;
    bf16x8 a[2];
#pragma unroll
    for (int m = 0; m < 2; ++m) {
      const int row = w * 32 + m * 16 + l15;
      a[m] = *(const bf16x8*)(A + row * 64 + ((kq ^ ((row >> 1) & 3)) << 4));
    }
#pragma unroll
    for (int n = 0; n < 9; ++n) {
      bf16x8 b = *(const bf16x8*)(Bt + n * 1024 + lane * 16);
      acc[0][n] = __builtin_amdgcn_mfma_f32_16x16x32_bf16(a[0], b, acc[0][n], 0, 0, 0);
      acc[1][n] = __builtin_amdgcn_mfma_f32_16x16x32_bf16(a[1], b, acc[1][n], 0, 0, 0);
    }
  };

  // ---- stage 1: h1_pre = [pe|cell|cond] @ Wcat_p  (K = 1056 = 33 x 32) ----
  preloadA(0); stageB(0, 0); writeA(0);
  for (int kt = 0; kt < 33; ++kt) {
    __syncthreads();
    const int buf = kt & 1;
    if (kt + 1 < 33) { preloadA(kt + 1); stageB(kt + 1, buf ^ 1); }
    compute1(buf);
    if (kt + 1 < 33) writeA(buf ^ 1);
  }
  __syncthreads();   // stage1 buffers dead after this; h1 region may be written

  // ---- epilogue 1: +c_p, lrelu, -> h1 (bf16, swizzled), zero K-pad --------
  {
    const float* cp = cvec + p * 144;
#pragma unroll
    for (int m = 0; m < 2; ++m) {
      const int rb = w * 32 + m * 16 + (kq << 2);
#pragma unroll
      for (int n = 0; n < 9; ++n) {
        const int col = n * 16 + l15;
        const float cb = cp[col];
#pragma unroll
        for (int i = 0; i < 4; ++i) {
          const int row = rb + i;
          float v = acc[m][n][i] + cb;
          v = v > 0.f ? v : 0.2f * v;
          const int u = (col >> 3) ^ ((row >> 1) & 3);
          *(u16*)(h1 + row * 320 + u * 16 + ((col & 7) << 1)) = f2bf(v);
        }
      }
    }
    const int uz = (18 + sh) ^ sf;       // zero cols 144..159
    u16x8 z = {0, 0, 0, 0, 0, 0, 0, 0};
    *(u16x8*)(h1 + sr * 320 + uz * 16) = z;
  }

  // ---- stage 2: h2 = lrelu(h1 @ W2_p + b2)  (K = 160 = 5 x 32, N = 272) ---
  f32x4 acc2[2][17];
#pragma unroll
  for (int m = 0; m < 2; ++m)
#pragma unroll
    for (int n = 0; n < 17; ++n) acc2[m][n] = fz;

  const u16* w2src = W2pk + (size_t)p * (5 * 8704);
  for (int kt = 0; kt < 5; ++kt) {
    for (int i = w; i < 17; i += 4)
      gl_lds16(w2src + kt * 8704 + i * 512 + lane * 8, B2 + i * 1024);
    __syncthreads();     // stage done (vmcnt drained) + h1 visible (iter 0)
    bf16x8 a[2];
#pragma unroll
    for (int m = 0; m < 2; ++m) {
      const int row = w * 32 + m * 16 + l15;
      const int u = (kt * 4 + kq) ^ ((row >> 1) & 3);
      a[m] = *(const bf16x8*)(h1 + row * 320 + u * 16);
    }
#pragma unroll
    for (int n = 0; n < 17; ++n) {
      bf16x8 b = *(const bf16x8*)(B2 + n * 1024 + lane * 16);
      acc2[0][n] = __builtin_amdgcn_mfma_f32_16x16x32_bf16(a[0], b, acc2[0][n], 0, 0, 0);
      acc2[1][n] = __builtin_amdgcn_mfma_f32_16x16x32_bf16(a[1], b, acc2[1][n], 0, 0, 0);
    }
    __syncthreads();     // reads done before next stage overwrites B2
  }

  // ---- stage 3: out = lrelu(h2) . w3 + b3 (in-register + shfl reduce) -----
  {
    const float* w3p = W3 + p * 272;
    const float* b2p = b2 + p * 272;
    const float b3v = b3[p];
    float w3v[17], b2v[17];
#pragma unroll
    for (int n = 0; n < 17; ++n) { w3v[n] = w3p[n * 16 + l15]; b2v[n] = b2p[n * 16 + l15]; }
#pragma unroll
    for (int m = 0; m < 2; ++m) {
#pragma unroll
      for (int i = 0; i < 4; ++i) {
        float s = 0.f;
#pragma unroll
        for (int n = 0; n < 17; ++n) {
          float h = acc2[m][n][i] + b2v[n];
          h = h > 0.f ? h : 0.2f * h;
          s += h * w3v[n];
        }
        s += __shfl_xor(s, 1);
        s += __shfl_xor(s, 2);
        s += __shfl_xor(s, 4);
        s += __shfl_xor(s, 8);
        if (l15 == 0) {
          const int row = w * 32 + m * 16 + (kq << 2) + i;
          out[(size_t)(b0 + row) * 64 + p] = s + b3v;
        }
      }
    }
  }
}

// ---------------------------------------------------------------------------
extern "C" void kernel_launch(void* const* d_in, const int* in_sizes, int n_in,
                              void* d_out, int out_size, void* d_ws, size_t ws_size,
                              hipStream_t stream) {
  const float* cell   = (const float*)d_in[0];   // [4096,512]
  const float* cond   = (const float*)d_in[1];   // [4096,32]
  const float* pe     = (const float*)d_in[2];   // [4096,64,512]
  const float* projW  = (const float*)d_in[3];   // [512,512]
  const float* projb  = (const float*)d_in[4];   // [512]
  const float* transW = (const float*)d_in[5];   // [1056,544]
  const float* transb = (const float*)d_in[6];   // [544]
  const float* W1     = (const float*)d_in[7];   // [64,544,136]
  const float* b1     = (const float*)d_in[8];   // [64,136]
  const float* W2     = (const float*)d_in[9];   // [64,136,272]
  const float* b2     = (const float*)d_in[10];  // [64,272]
  const float* W3     = (const float*)d_in[11];  // [64,272,1]
  const float* b3     = (const float*)d_in[12];  // [64,1]
  float* out = (float*)d_out;

  char* ws = (char*)d_ws;
  float* G    = (float*)(ws);                    // 1056*544*4   = 2,297,856
  u16*  W1pk  = (u16*)(ws + 2297856);            // 64*17*9216   = 10,027,008
  u16*  Wpk   = (u16*)(ws + 12324864);           // 64*33*9216   = 19,464,192
  u16*  W2pk  = (u16*)(ws + 31789056);           // 64*5*17408   = 5,570,560
  float* dvec = (float*)(ws + 37359616);         // 544*4
  float* cvec = (float*)(ws + 37361792);         // 64*144*4     (end 37,398,656)

  k_g      <<<32,   256, 0, stream>>>(projW, transW, G);
  k_gcopy  <<<289,  256, 0, stream>>>(transW, G);
  k_d      <<<3,    256, 0, stream>>>(projb, transW, transb, dvec);
  k_c      <<<36,   256, 0, stream>>>(dvec, W1, b1, cvec);
  k_pack_w1<<<2448, 256, 0, stream>>>(W1, W1pk);
  k_pack_w2<<<1360, 256, 0, stream>>>(W2, W2pk);
  k_pk3    <<<dim3(9, 64),  256, 0, stream>>>(G, W1pk, Wpk);
  k_main   <<<dim3(32, 64), 256, 0, stream>>>(cell, cond, pe, Wpk, W2pk, cvec, b2, W3, b3, out);
}

// Round 2
// 328.895 us; speedup vs baseline: 2.8465x; 2.8465x over previous
//
#include <hip/hip_runtime.h>

// ---------------------------------------------------------------------------
// PredictModelWithCLasses: fused per-protein MLP on MI355X (gfx950).
//
// Math: out[b,p] = w3_p . lrelu( W2_p^T . lrelu( Wcat_p^T . [pe(b,p)|spot(b)] + c_p ) + b2_p ) + b3_p
// where Wcat_p = [proj_W @ TW_top ; TW_bot] @ W1_p   (1056 x 136), fused since
// there is NO activation between trans_dim and W1.
//
// Round 2: k_g rewritten as LDS-tiled f32 GEMM (was 589 us @ 1% occupancy);
// k_d / k_c parallelized with K-split + LDS reduction.
// ---------------------------------------------------------------------------

typedef short bf16x8 __attribute__((ext_vector_type(8)));   // 8 bf16 (raw bits)
typedef unsigned short u16;
typedef u16 u16x8 __attribute__((ext_vector_type(8)));
typedef float f32x4 __attribute__((ext_vector_type(4)));

typedef const void __attribute__((address_space(1)))* gas_p;
typedef void __attribute__((address_space(3)))* las_p;

__device__ __forceinline__ void gl_lds16(const void* g, void* l) {
  // async global->LDS, 16B per lane; LDS dest = uniform base + lane*16
  __builtin_amdgcn_global_load_lds((gas_p)g, (las_p)l, 16, 0, 0);
}

__device__ __forceinline__ u16 f2bf(float f) {  // f32 -> bf16 RTNE
  union { float f; unsigned u; } x; x.f = f;
  return (u16)((x.u + 0x7FFFu + ((x.u >> 16) & 1u)) >> 16);
}

// ---------------- tiny precompute kernels ----------------------------------

// G top: G[r][c] = sum_k proj_W[r][k] * trans_W[k][c]   (r<512)
// Tiled f32 GEMM: 64x64 tile, BK=16, grid (8,9), 256 thr, 4x4 acc/thread.
__global__ __launch_bounds__(256)
void k_g(const float* __restrict__ projW, const float* __restrict__ transW,
         float* __restrict__ G) {
  __shared__ float As[16][68];   // [kk][r]   (68: float4-aligned rows, pad)
  __shared__ float Bs[16][68];   // [kk][c]
  const int t = threadIdx.x;
  const int m0 = blockIdx.x * 64, c0 = blockIdx.y * 64;
  const int tx = t & 15, ty = t >> 4;          // 16x16 thread tile
  const int ar = t >> 2, akk = (t & 3) * 4;    // A loader: row, k-quad
  const int bkk = t >> 4, bcc = (t & 15) * 4;  // B loader: k, col-quad
  const bool bok = (c0 + bcc) < 544;
  float acc[4][4];
#pragma unroll
  for (int i = 0; i < 4; ++i)
#pragma unroll
    for (int j = 0; j < 4; ++j) acc[i][j] = 0.f;

  for (int k0 = 0; k0 < 512; k0 += 16) {
    const float4 av = *(const float4*)(projW + (size_t)(m0 + ar) * 512 + k0 + akk);
    float4 bv = {0.f, 0.f, 0.f, 0.f};
    if (bok) bv = *(const float4*)(transW + (size_t)(k0 + bkk) * 544 + c0 + bcc);
    __syncthreads();
    As[akk + 0][ar] = av.x; As[akk + 1][ar] = av.y;
    As[akk + 2][ar] = av.z; As[akk + 3][ar] = av.w;
    *(float4*)&Bs[bkk][bcc] = bv;
    __syncthreads();
#pragma unroll
    for (int kk = 0; kk < 16; ++kk) {
      const float4 a = *(const float4*)&As[kk][ty * 4];
      const float4 b = *(const float4*)&Bs[kk][tx * 4];
      const float aa[4] = {a.x, a.y, a.z, a.w};
      const float bb[4] = {b.x, b.y, b.z, b.w};
#pragma unroll
      for (int i = 0; i < 4; ++i)
#pragma unroll
        for (int j = 0; j < 4; ++j) acc[i][j] += aa[i] * bb[j];
    }
  }
  if ((c0 + tx * 4) < 544) {
#pragma unroll
    for (int i = 0; i < 4; ++i) {
      float4 v = {acc[i][0], acc[i][1], acc[i][2], acc[i][3]};
      *(float4*)(G + (size_t)(m0 + ty * 4 + i) * 544 + c0 + tx * 4) = v;
    }
  }
}

// G bottom: copy trans_W rows 512..1055
__global__ void k_gcopy(const float* __restrict__ transW, float* __restrict__ G) {
  const int idx = blockIdx.x * 256 + threadIdx.x;   // float4 units, 73984 total
  if (idx >= 73984) return;
  ((float4*)G)[69632 + idx] = ((const float4*)transW)[69632 + idx];
}

// d[c] = proj_b @ TW_top + trans_b   (grid 17, 8-way K-split)
__global__ void k_d(const float* __restrict__ projb, const float* __restrict__ transW,
                    const float* __restrict__ transb, float* __restrict__ dvec) {
  __shared__ float red[256];
  const int t = threadIdx.x;
  const int c = blockIdx.x * 32 + (t & 31);
  const int kp = t >> 5;                       // 0..7, 64 k each
  float s = 0.f;
  for (int k = kp * 64; k < kp * 64 + 64; ++k) s += projb[k] * transW[(size_t)k * 544 + c];
  red[t] = s;
  __syncthreads();
  if (t < 32) {
    float v = red[t];
#pragma unroll
    for (int j = 1; j < 8; ++j) v += red[t + 32 * j];
    dvec[blockIdx.x * 32 + t] = v + transb[blockIdx.x * 32 + t];
  }
}

// c_p[col] = d @ W1_p + b1_p  (padded to 144). grid (64,9), 16-way K-split.
__global__ void k_c(const float* __restrict__ dvec, const float* __restrict__ W1,
                    const float* __restrict__ b1, float* __restrict__ cvec) {
  __shared__ float red[256];
  const int t = threadIdx.x;
  const int p = blockIdx.x, cg = blockIdx.y;
  const int col = cg * 16 + (t & 15);
  const int kp = t >> 4;                       // 0..15, 34 k each
  float s = 0.f;
  if (col < 136) {
    const float* w = W1 + (size_t)p * 544 * 136;
    for (int k = kp * 34; k < kp * 34 + 34; ++k) s += dvec[k] * w[(size_t)k * 136 + col];
  }
  red[t] = s;
  __syncthreads();
  if (t < 16) {
    float v = 0.f;
#pragma unroll
    for (int j = 0; j < 16; ++j) v += red[j * 16 + t];
    const int c2 = cg * 16 + t;
    cvec[p * 144 + c2] = (c2 < 136) ? v + b1[p * 136 + c2] : 0.f;
  }
}

// Pack W1 into MFMA-B-fragment order, bf16:
// dest ushort off = ((p*17+kt)*9 + n)*512 + (kblk*16+col)*8 + j ; value W1[p][kt*32+kblk*8+j][n*16+col] (0 if col>=136)
__global__ void k_pack_w1(const float* __restrict__ W1, u16* __restrict__ W1pk) {
  const int uid = blockIdx.x * 256 + threadIdx.x;    // < 64*17*9*64 = 626688
  const int unit = uid & 63;
  const int rest = uid >> 6;
  const int n = rest % 9;
  const int tile = rest / 9;        // p*17 + kt
  const int kt = tile % 17;
  const int pp = tile / 17;
  const int kb = unit >> 4, cl = unit & 15;
  const int colg = n * 16 + cl;
  u16x8 v;
#pragma unroll
  for (int j = 0; j < 8; ++j) {
    const int k = kt * 32 + kb * 8 + j;              // < 544
    v[j] = (colg < 136) ? f2bf(W1[((size_t)pp * 544 + k) * 136 + colg]) : (u16)0;
  }
  *(u16x8*)(W1pk + (size_t)uid * 8) = v;
}

// Pack W2 (K padded 136->160): dest off = ((p*5+kt)*17 + n)*512 + (kblk*16+col)*8 + j
__global__ void k_pack_w2(const float* __restrict__ W2, u16* __restrict__ W2pk) {
  const int uid = blockIdx.x * 256 + threadIdx.x;    // < 64*5*17*64 = 348160
  const int unit = uid & 63;
  const int rest = uid >> 6;
  const int n = rest % 17;
  const int tile = rest / 17;       // p*5 + kt
  const int kt = tile % 5;
  const int pp = tile / 5;
  const int kb = unit >> 4, cl = unit & 15;
  const int colg = n * 16 + cl;                      // < 272
  u16x8 v;
#pragma unroll
  for (int j = 0; j < 8; ++j) {
    const int k = kt * 32 + kb * 8 + j;              // < 160
    v[j] = (k < 136) ? f2bf(W2[((size_t)pp * 136 + k) * 272 + colg]) : (u16)0;
  }
  *(u16x8*)(W2pk + (size_t)uid * 8) = v;
}

// ---------------- grouped GEMM: Wcat_p = G @ W1_p ---------------------------
// M=1056 (9 tiles of 128, guarded), K=544 (17 steps), N=144. Output written in
// the main kernel's B-fragment packed layout.
__global__ __launch_bounds__(256, 2)
void k_pk3(const float* __restrict__ G, const u16* __restrict__ W1pk,
           u16* __restrict__ Wpk) {
  __shared__ char smem[34816];
  char* const Ab0 = smem;            // 2 x 8192
  char* const Bb0 = smem + 16384;    // 2 x 9216
  const int t = threadIdx.x, lane = t & 63, w = t >> 6;
  const int l15 = lane & 15, kq = lane >> 4;
  const int mt = blockIdx.x, p = blockIdx.y;
  const int sr = t >> 1, sh = t & 1, sf = (sr >> 1) & 3;
  const int gr = mt * 128 + sr;
  const bool aval = (gr < 1056);

  const f32x4 fz = {0.f, 0.f, 0.f, 0.f};
  f32x4 acc[2][9];
#pragma unroll
  for (int m = 0; m < 2; ++m)
#pragma unroll
    for (int n = 0; n < 9; ++n) acc[m][n] = fz;

  const u16* wsrc = W1pk + (size_t)p * (17 * 4608);

  float4 pv[4];
  auto preloadA = [&](int kt) {
    if (aval) {
      const float* s = G + (size_t)gr * 544 + kt * 32 + sh * 16;
#pragma unroll
      for (int j = 0; j < 4; ++j) pv[j] = *(const float4*)(s + j * 4);
    } else {
      const float4 z4 = {0.f, 0.f, 0.f, 0.f};
#pragma unroll
      for (int j = 0; j < 4; ++j) pv[j] = z4;
    }
  };
  auto writeA = [&](int buf) {
    u16x8 v0, v1;
    v0[0] = f2bf(pv[0].x); v0[1] = f2bf(pv[0].y); v0[2] = f2bf(pv[0].z); v0[3] = f2bf(pv[0].w);
    v0[4] = f2bf(pv[1].x); v0[5] = f2bf(pv[1].y); v0[6] = f2bf(pv[1].z); v0[7] = f2bf(pv[1].w);
    v1[0] = f2bf(pv[2].x); v1[1] = f2bf(pv[2].y); v1[2] = f2bf(pv[2].z); v1[3] = f2bf(pv[2].w);
    v1[4] = f2bf(pv[3].x); v1[5] = f2bf(pv[3].y); v1[6] = f2bf(pv[3].z); v1[7] = f2bf(pv[3].w);
    char* dst = Ab0 + buf * 8192 + sr * 64;
    *(u16x8*)(dst + ((((sh << 1)) ^ sf) << 4)) = v0;
    *(u16x8*)(dst + ((((sh << 1) | 1) ^ sf) << 4)) = v1;
  };
  auto stageB = [&](int kt, int buf) {
    const u16* src = wsrc + kt * 4608;
    char* dst = Bb0 + buf * 9216;
    for (int i = w; i < 9; i += 4) gl_lds16(src + i * 512 + lane * 8, dst + i * 1024);
  };
  auto compute = [&](int buf) {
    const char* A = Ab0 + buf * 8192;
    const char* Bt = Bb0 + buf * 9216;
    bf16x8 a[2];
#pragma unroll
    for (int m = 0; m < 2; ++m) {
      const int row = w * 32 + m * 16 + l15;
      a[m] = *(const bf16x8*)(A + row * 64 + ((kq ^ ((row >> 1) & 3)) << 4));
    }
#pragma unroll
    for (int n = 0; n < 9; ++n) {
      bf16x8 b = *(const bf16x8*)(Bt + n * 1024 + lane * 16);
      acc[0][n] = __builtin_amdgcn_mfma_f32_16x16x32_bf16(a[0], b, acc[0][n], 0, 0, 0);
      acc[1][n] = __builtin_amdgcn_mfma_f32_16x16x32_bf16(a[1], b, acc[1][n], 0, 0, 0);
    }
  };

  preloadA(0); stageB(0, 0); writeA(0);
  for (int kt = 0; kt < 17; ++kt) {
    __syncthreads();
    const int buf = kt & 1;
    if (kt + 1 < 17) { preloadA(kt + 1); stageB(kt + 1, buf ^ 1); }
    compute(buf);
    if (kt + 1 < 17) writeA(buf ^ 1);
  }

  // epilogue: scatter into Wpk fragment layout (row = k index of main GEMM)
#pragma unroll
  for (int m = 0; m < 2; ++m)
#pragma unroll
    for (int n = 0; n < 9; ++n)
#pragma unroll
      for (int i = 0; i < 4; ++i) {
        const int row = mt * 128 + w * 32 + m * 16 + (kq << 2) + i;
        if (row < 1056) {
          const int ktw = row >> 5, kk = row & 31;
          const size_t off = (size_t)(p * 33 + ktw) * 4608 + n * 512 +
                             ((kk >> 3) * 16 + l15) * 8 + (kk & 7);
          Wpk[off] = f2bf(acc[m][n][i]);
        }
      }
}

// ---------------- fused main kernel -----------------------------------------
__global__ __launch_bounds__(256, 2)
void k_main(const float* __restrict__ cell, const float* __restrict__ cond,
            const float* __restrict__ pe,
            const u16* __restrict__ Wpk, const u16* __restrict__ W2pk,
            const float* __restrict__ cvec, const float* __restrict__ b2,
            const float* __restrict__ W3, const float* __restrict__ b3,
            float* __restrict__ out) {
  __shared__ char smem[58368];
  char* const Ab0 = smem;            // stage1 A dbuf: 2 x 8192
  char* const Bb0 = smem + 16384;    // stage1 B dbuf: 2 x 9216
  char* const h1  = smem + 17408;    // 128 x 320B (overlaps stage1 bufs; used after)
  char* const B2  = smem;            // stage2 B: 17408B (overlaps dead stage1 bufs)

  const int t = threadIdx.x, lane = t & 63, w = t >> 6;
  const int l15 = lane & 15, kq = lane >> 4;
  const int p = blockIdx.y;
  const int b0 = blockIdx.x * 128;
  const int sr = t >> 1, sh = t & 1, sf = (sr >> 1) & 3;
  const long gr = b0 + sr;

  const f32x4 fz = {0.f, 0.f, 0.f, 0.f};
  f32x4 acc[2][9];
#pragma unroll
  for (int m = 0; m < 2; ++m)
#pragma unroll
    for (int n = 0; n < 9; ++n) acc[m][n] = fz;

  const u16* wsrc = Wpk + (size_t)p * (33 * 4608);

  float4 pv[4];
  auto preloadA = [&](int kt) {
    const float* s;
    if (kt < 16)      s = pe + ((gr * 64 + p) << 9) + kt * 32 + sh * 16;
    else if (kt < 32) s = cell + (gr << 9) + (kt - 16) * 32 + sh * 16;
    else              s = cond + (gr << 5) + sh * 16;
#pragma unroll
    for (int j = 0; j < 4; ++j) pv[j] = *(const float4*)(s + j * 4);
  };
  auto writeA = [&](int buf) {
    u16x8 v0, v1;
    v0[0] = f2bf(pv[0].x); v0[1] = f2bf(pv[0].y); v0[2] = f2bf(pv[0].z); v0[3] = f2bf(pv[0].w);
    v0[4] = f2bf(pv[1].x); v0[5] = f2bf(pv[1].y); v0[6] = f2bf(pv[1].z); v0[7] = f2bf(pv[1].w);
    v1[0] = f2bf(pv[2].x); v1[1] = f2bf(pv[2].y); v1[2] = f2bf(pv[2].z); v1[3] = f2bf(pv[2].w);
    v1[4] = f2bf(pv[3].x); v1[5] = f2bf(pv[3].y); v1[6] = f2bf(pv[3].z); v1[7] = f2bf(pv[3].w);
    char* dst = Ab0 + buf * 8192 + sr * 64;
    *(u16x8*)(dst + ((((sh << 1)) ^ sf) << 4)) = v0;
    *(u16x8*)(dst + ((((sh << 1) | 1) ^ sf) << 4)) = v1;
  };
  auto stageB = [&](int kt, int buf) {
    const u16* src = wsrc + kt * 4608;
    char* dst = Bb0 + buf * 9216;
    for (int i = w; i < 9; i += 4) gl_lds16(src + i * 512 + lane * 8, dst + i * 1024);
  };
  auto compute1 = [&](int buf) {
    const char* A = Ab0 + buf * 8192;
    const char* Bt = Bb0 + buf * 9216;
    bf16x8 a[2];
#pragma unroll
    for (int m = 0; m < 2; ++m) {
      const int row = w * 32 + m * 16 + l15;
      a[m] = *(const bf16x8*)(A + row * 64 + ((kq ^ ((row >> 1) & 3)) << 4));
    }
#pragma unroll
    for (int n = 0; n < 9; ++n) {
      bf16x8 b = *(const bf16x8*)(Bt + n * 1024 + lane * 16);
      acc[0][n] = __builtin_amdgcn_mfma_f32_16x16x32_bf16(a[0], b, acc[0][n], 0, 0, 0);
      acc[1][n] = __builtin_amdgcn_mfma_f32_16x16x32_bf16(a[1], b, acc[1][n], 0, 0, 0);
    }
  };

  // ---- stage 1: h1_pre = [pe|cell|cond] @ Wcat_p  (K = 1056 = 33 x 32) ----
  preloadA(0); stageB(0, 0); writeA(0);
  for (int kt = 0; kt < 33; ++kt) {
    __syncthreads();
    const int buf = kt & 1;
    if (kt + 1 < 33) { preloadA(kt + 1); stageB(kt + 1, buf ^ 1); }
    compute1(buf);
    if (kt + 1 < 33) writeA(buf ^ 1);
  }
  __syncthreads();   // stage1 buffers dead after this; h1 region may be written

  // ---- epilogue 1: +c_p, lrelu, -> h1 (bf16, swizzled), zero K-pad --------
  {
    const float* cp = cvec + p * 144;
#pragma unroll
    for (int m = 0; m < 2; ++m) {
      const int rb = w * 32 + m * 16 + (kq << 2);
#pragma unroll
      for (int n = 0; n < 9; ++n) {
        const int col = n * 16 + l15;
        const float cb = cp[col];
#pragma unroll
        for (int i = 0; i < 4; ++i) {
          const int row = rb + i;
          float v = acc[m][n][i] + cb;
          v = v > 0.f ? v : 0.2f * v;
          const int u = (col >> 3) ^ ((row >> 1) & 3);
          *(u16*)(h1 + row * 320 + u * 16 + ((col & 7) << 1)) = f2bf(v);
        }
      }
    }
    const int uz = (18 + sh) ^ sf;       // zero cols 144..159
    u16x8 z = {0, 0, 0, 0, 0, 0, 0, 0};
    *(u16x8*)(h1 + sr * 320 + uz * 16) = z;
  }

  // ---- stage 2: h2 = lrelu(h1 @ W2_p + b2)  (K = 160 = 5 x 32, N = 272) ---
  f32x4 acc2[2][17];
#pragma unroll
  for (int m = 0; m < 2; ++m)
#pragma unroll
    for (int n = 0; n < 17; ++n) acc2[m][n] = fz;

  const u16* w2src = W2pk + (size_t)p * (5 * 8704);
  for (int kt = 0; kt < 5; ++kt) {
    for (int i = w; i < 17; i += 4)
      gl_lds16(w2src + kt * 8704 + i * 512 + lane * 8, B2 + i * 1024);
    __syncthreads();     // stage done (vmcnt drained) + h1 visible (iter 0)
    bf16x8 a[2];
#pragma unroll
    for (int m = 0; m < 2; ++m) {
      const int row = w * 32 + m * 16 + l15;
      const int u = (kt * 4 + kq) ^ ((row >> 1) & 3);
      a[m] = *(const bf16x8*)(h1 + row * 320 + u * 16);
    }
#pragma unroll
    for (int n = 0; n < 17; ++n) {
      bf16x8 b = *(const bf16x8*)(B2 + n * 1024 + lane * 16);
      acc2[0][n] = __builtin_amdgcn_mfma_f32_16x16x32_bf16(a[0], b, acc2[0][n], 0, 0, 0);
      acc2[1][n] = __builtin_amdgcn_mfma_f32_16x16x32_bf16(a[1], b, acc2[1][n], 0, 0, 0);
    }
    __syncthreads();     // reads done before next stage overwrites B2
  }

  // ---- stage 3: out = lrelu(h2) . w3 + b3 (in-register + shfl reduce) -----
  {
    const float* w3p = W3 + p * 272;
    const float* b2p = b2 + p * 272;
    const float b3v = b3[p];
    float w3v[17], b2v[17];
#pragma unroll
    for (int n = 0; n < 17; ++n) { w3v[n] = w3p[n * 16 + l15]; b2v[n] = b2p[n * 16 + l15]; }
#pragma unroll
    for (int m = 0; m < 2; ++m) {
#pragma unroll
      for (int i = 0; i < 4; ++i) {
        float s = 0.f;
#pragma unroll
        for (int n = 0; n < 17; ++n) {
          float h = acc2[m][n][i] + b2v[n];
          h = h > 0.f ? h : 0.2f * h;
          s += h * w3v[n];
        }
        s += __shfl_xor(s, 1);
        s += __shfl_xor(s, 2);
        s += __shfl_xor(s, 4);
        s += __shfl_xor(s, 8);
        if (l15 == 0) {
          const int row = w * 32 + m * 16 + (kq << 2) + i;
          out[(size_t)(b0 + row) * 64 + p] = s + b3v;
        }
      }
    }
  }
}

// ---------------------------------------------------------------------------
extern "C" void kernel_launch(void* const* d_in, const int* in_sizes, int n_in,
                              void* d_out, int out_size, void* d_ws, size_t ws_size,
                              hipStream_t stream) {
  const float* cell   = (const float*)d_in[0];   // [4096,512]
  const float* cond   = (const float*)d_in[1];   // [4096,32]
  const float* pe     = (const float*)d_in[2];   // [4096,64,512]
  const float* projW  = (const float*)d_in[3];   // [512,512]
  const float* projb  = (const float*)d_in[4];   // [512]
  const float* transW = (const float*)d_in[5];   // [1056,544]
  const float* transb = (const float*)d_in[6];   // [544]
  const float* W1     = (const float*)d_in[7];   // [64,544,136]
  const float* b1     = (const float*)d_in[8];   // [64,136]
  const float* W2     = (const float*)d_in[9];   // [64,136,272]
  const float* b2     = (const float*)d_in[10];  // [64,272]
  const float* W3     = (const float*)d_in[11];  // [64,272,1]
  const float* b3     = (const float*)d_in[12];  // [64,1]
  float* out = (float*)d_out;

  char* ws = (char*)d_ws;
  float* G    = (float*)(ws);                    // 1056*544*4   = 2,297,856
  u16*  W1pk  = (u16*)(ws + 2297856);            // 64*17*9216   = 10,027,008
  u16*  Wpk   = (u16*)(ws + 12324864);           // 64*33*9216   = 19,464,192
  u16*  W2pk  = (u16*)(ws + 31789056);           // 64*5*17408   = 5,570,560
  float* dvec = (float*)(ws + 37359616);         // 544*4
  float* cvec = (float*)(ws + 37361792);         // 64*144*4     (end 37,398,656)

  k_g      <<<dim3(8, 9),   256, 0, stream>>>(projW, transW, G);
  k_gcopy  <<<289,  256, 0, stream>>>(transW, G);
  k_d      <<<17,   256, 0, stream>>>(projb, transW, transb, dvec);
  k_c      <<<dim3(64, 9),  256, 0, stream>>>(dvec, W1, b1, cvec);
  k_pack_w1<<<2448, 256, 0, stream>>>(W1, W1pk);
  k_pack_w2<<<1360, 256, 0, stream>>>(W2, W2pk);
  k_pk3    <<<dim3(9, 64),  256, 0, stream>>>(G, W1pk, Wpk);
  k_main   <<<dim3(32, 64), 256, 0, stream>>>(cell, cond, pe, Wpk, W2pk, cvec, b2, W3, b3, out);
}

// Round 4
// 326.382 us; speedup vs baseline: 2.8684x; 1.0077x over previous
//
#include <hip/hip_runtime.h>

// ---------------------------------------------------------------------------
// PredictModelWithCLasses: fused per-protein MLP on MI355X (gfx950).
//
// out[b,p] = w3_p . lrelu( W2_p^T . lrelu( Wcat_p^T . [pe(b,p)|spot(b)] + c_p ) + b2_p ) + b3_p
// Wcat_p = [proj_W @ TW_top ; TW_bot] @ W1_p  (1056x136) — fusable since there
// is no activation between trans_dim and W1.
//
// Round 4: r3 failed POST-TIMING revalidation (race under graph replay).
// Suspect: stage2 double-buffer in k_main (only sync-structure change).
// -> stage2 reverted to the r2-proven single-buffer stage/barrier/MFMA/barrier.
// Keeping: fused k_pre, k_pk3 epilogue-cvec fusion, 2Mx2N stage1 wave split,
// XCD-aware swizzle, h1 in non-aliasing LDS region.
// ---------------------------------------------------------------------------

typedef short bf16x8 __attribute__((ext_vector_type(8)));   // 8 bf16 (raw bits)
typedef unsigned short u16;
typedef u16 u16x8 __attribute__((ext_vector_type(8)));
typedef float f32x4 __attribute__((ext_vector_type(4)));

typedef const void __attribute__((address_space(1)))* gas_p;
typedef void __attribute__((address_space(3)))* las_p;

__device__ __forceinline__ void gl_lds16(const void* g, void* l) {
  __builtin_amdgcn_global_load_lds((gas_p)g, (las_p)l, 16, 0, 0);
}

__device__ __forceinline__ u16 f2bf(float f) {  // f32 -> bf16 RTNE
  union { float f; unsigned u; } x; x.f = f;
  return (u16)((x.u + 0x7FFFu + ((x.u >> 16) & 1u)) >> 16);
}

// ---------------- fused precompute (block-range dispatch) -------------------
// blocks [0,72): G top = projW @ TW_top (64x64 tile f32 GEMM)
// blocks [72,361): G rows 512..1055 = copy TW_bot
// blocks [361,378): G row 1056 = proj_b @ TW_top + trans_b
// blocks [378,391): G rows 1057..1151 = 0
// blocks [391,2839): pack W1 -> MFMA-B bf16 fragments
// blocks [2839,4199): pack W2 -> MFMA-B bf16 fragments (K pad 136->160)
__global__ __launch_bounds__(256)
void k_pre(const float* __restrict__ projW, const float* __restrict__ transW,
           const float* __restrict__ projb, const float* __restrict__ transb,
           const float* __restrict__ W1, const float* __restrict__ W2,
           float* __restrict__ G, u16* __restrict__ W1pk, u16* __restrict__ W2pk) {
  __shared__ float As[16][68];
  __shared__ float Bs[16][68];
  const int bb = blockIdx.x, t = threadIdx.x;

  if (bb < 72) {                       // ---- G top GEMM ----
    const int m0 = (bb & 7) * 64, c0 = (bb >> 3) * 64;
    const int tx = t & 15, ty = t >> 4;
    const int ar = t >> 2, akk = (t & 3) * 4;
    const int bkk = t >> 4, bcc = (t & 15) * 4;
    const bool bok = (c0 + bcc) < 544;
    float acc[4][4];
#pragma unroll
    for (int i = 0; i < 4; ++i)
#pragma unroll
      for (int j = 0; j < 4; ++j) acc[i][j] = 0.f;
    for (int k0 = 0; k0 < 512; k0 += 16) {
      const float4 av = *(const float4*)(projW + (size_t)(m0 + ar) * 512 + k0 + akk);
      float4 bv = {0.f, 0.f, 0.f, 0.f};
      if (bok) bv = *(const float4*)(transW + (size_t)(k0 + bkk) * 544 + c0 + bcc);
      __syncthreads();
      As[akk + 0][ar] = av.x; As[akk + 1][ar] = av.y;
      As[akk + 2][ar] = av.z; As[akk + 3][ar] = av.w;
      *(float4*)&Bs[bkk][bcc] = bv;
      __syncthreads();
#pragma unroll
      for (int kk = 0; kk < 16; ++kk) {
        const float4 a = *(const float4*)&As[kk][ty * 4];
        const float4 b = *(const float4*)&Bs[kk][tx * 4];
        const float aa[4] = {a.x, a.y, a.z, a.w};
        const float bb2[4] = {b.x, b.y, b.z, b.w};
#pragma unroll
        for (int i = 0; i < 4; ++i)
#pragma unroll
          for (int j = 0; j < 4; ++j) acc[i][j] += aa[i] * bb2[j];
      }
    }
    if ((c0 + tx * 4) < 544) {
#pragma unroll
      for (int i = 0; i < 4; ++i) {
        float4 v = {acc[i][0], acc[i][1], acc[i][2], acc[i][3]};
        *(float4*)(G + (size_t)(m0 + ty * 4 + i) * 544 + c0 + tx * 4) = v;
      }
    }
  } else if (bb < 361) {               // ---- G rows 512..1055 copy ----
    const int idx = (bb - 72) * 256 + t;
    if (idx < 73984) ((float4*)G)[69632 + idx] = ((const float4*)transW)[69632 + idx];
  } else if (bb < 378) {               // ---- G row 1056 = d-vector ----
    __shared__ float red[256];
    const int c = (bb - 361) * 32 + (t & 31);
    const int kp = t >> 5;
    float s = 0.f;
    for (int k = kp * 64; k < kp * 64 + 64; ++k) s += projb[k] * transW[(size_t)k * 544 + c];
    red[t] = s;
    __syncthreads();
    if (t < 32) {
      float v = red[t];
#pragma unroll
      for (int j = 1; j < 8; ++j) v += red[t + 32 * j];
      const int cc = (bb - 361) * 32 + t;
      G[(size_t)1056 * 544 + cc] = v + transb[cc];
    }
  } else if (bb < 391) {               // ---- G rows 1057..1151 = 0 ----
    const int idx = (bb - 378) * 256 + t;
    const float4 z = {0.f, 0.f, 0.f, 0.f};
#pragma unroll
    for (int j = 0; j < 4; ++j) {
      const int k = idx + j * 3328;
      if (k < 12920) ((float4*)G)[143752 + k] = z;
    }
  } else if (bb < 2839) {              // ---- pack W1 ----
    const int uid = (bb - 391) * 256 + t;           // < 626688
    const int unit = uid & 63;
    const int rest = uid >> 6;
    const int n = rest % 9;
    const int tile = rest / 9;
    const int kt = tile % 17;
    const int pp = tile / 17;
    const int kb = unit >> 4, cl = unit & 15;
    const int colg = n * 16 + cl;
    u16x8 v;
#pragma unroll
    for (int j = 0; j < 8; ++j) {
      const int k = kt * 32 + kb * 8 + j;
      v[j] = (colg < 136) ? f2bf(W1[((size_t)pp * 544 + k) * 136 + colg]) : (u16)0;
    }
    *(u16x8*)(W1pk + (size_t)uid * 8) = v;
  } else {                             // ---- pack W2 ----
    const int uid = (bb - 2839) * 256 + t;          // < 348160
    const int unit = uid & 63;
    const int rest = uid >> 6;
    const int n = rest % 17;
    const int tile = rest / 17;
    const int kt = tile % 5;
    const int pp = tile / 5;
    const int kb = unit >> 4, cl = unit & 15;
    const int colg = n * 16 + cl;
    u16x8 v;
#pragma unroll
    for (int j = 0; j < 8; ++j) {
      const int k = kt * 32 + kb * 8 + j;
      v[j] = (k < 136) ? f2bf(W2[((size_t)pp * 136 + k) * 272 + colg]) : (u16)0;
    }
    *(u16x8*)(W2pk + (size_t)uid * 8) = v;
  }
}

// ---------------- grouped GEMM: Wcat_p = G @ W1_p ---------------------------
// M=1152 (9x128, rows>=1057 are zeros/discard), K=544 (17 steps), N=144.
// Row 1056 of the product = c_p - b1_p -> written to cvec (+b1, pad 0).
__global__ __launch_bounds__(256, 2)
void k_pk3(const float* __restrict__ G, const u16* __restrict__ W1pk,
           const float* __restrict__ b1, u16* __restrict__ Wpk,
           float* __restrict__ cvec) {
  __shared__ char smem[34816];
  char* const Ab0 = smem;            // 2 x 8192
  char* const Bb0 = smem + 16384;    // 2 x 9216
  const int t = threadIdx.x, lane = t & 63, w = t >> 6;
  const int l15 = lane & 15, kq = lane >> 4;
  const int mg = w >> 1, ng = w & 1;
  const int n0 = ng * 5, nn = ng ? 4 : 5;
  const int mt = blockIdx.x, p = blockIdx.y;
  const int sr = t >> 1, sh = t & 1, sf = (sr >> 1) & 3;
  const int gr = mt * 128 + sr;

  const f32x4 fz = {0.f, 0.f, 0.f, 0.f};
  f32x4 acc[4][5];
#pragma unroll
  for (int m = 0; m < 4; ++m)
#pragma unroll
    for (int n = 0; n < 5; ++n) acc[m][n] = fz;

  const u16* wsrc = W1pk + (size_t)p * (17 * 4608);

  float4 pv[4];
  auto preloadA = [&](int kt) {
    const float* s = G + (size_t)gr * 544 + kt * 32 + sh * 16;
#pragma unroll
    for (int j = 0; j < 4; ++j) pv[j] = *(const float4*)(s + j * 4);
  };
  auto writeA = [&](int buf) {
    u16x8 v0, v1;
    v0[0] = f2bf(pv[0].x); v0[1] = f2bf(pv[0].y); v0[2] = f2bf(pv[0].z); v0[3] = f2bf(pv[0].w);
    v0[4] = f2bf(pv[1].x); v0[5] = f2bf(pv[1].y); v0[6] = f2bf(pv[1].z); v0[7] = f2bf(pv[1].w);
    v1[0] = f2bf(pv[2].x); v1[1] = f2bf(pv[2].y); v1[2] = f2bf(pv[2].z); v1[3] = f2bf(pv[2].w);
    v1[4] = f2bf(pv[3].x); v1[5] = f2bf(pv[3].y); v1[6] = f2bf(pv[3].z); v1[7] = f2bf(pv[3].w);
    char* dst = Ab0 + buf * 8192 + sr * 64;
    *(u16x8*)(dst + ((((sh << 1)) ^ sf) << 4)) = v0;
    *(u16x8*)(dst + ((((sh << 1) | 1) ^ sf) << 4)) = v1;
  };
  auto stageB = [&](int kt, int buf) {
    const u16* src = wsrc + kt * 4608;
    char* dst = Bb0 + buf * 9216;
    for (int i = w; i < 9; i += 4) gl_lds16(src + i * 512 + lane * 8, dst + i * 1024);
  };
  auto compute = [&](int buf) {
    const char* A = Ab0 + buf * 8192;
    const char* Bt = Bb0 + buf * 9216;
    bf16x8 a[4];
#pragma unroll
    for (int m = 0; m < 4; ++m) {
      const int row = mg * 64 + m * 16 + l15;
      a[m] = *(const bf16x8*)(A + row * 64 + ((kq ^ ((row >> 1) & 3)) << 4));
    }
#pragma unroll
    for (int n = 0; n < 5; ++n) {
      if (n < nn) {
        bf16x8 b = *(const bf16x8*)(Bt + (n0 + n) * 1024 + lane * 16);
#pragma unroll
        for (int m = 0; m < 4; ++m)
          acc[m][n] = __builtin_amdgcn_mfma_f32_16x16x32_bf16(a[m], b, acc[m][n], 0, 0, 0);
      }
    }
  };

  preloadA(0); stageB(0, 0); writeA(0);
  for (int kt = 0; kt < 17; ++kt) {
    __syncthreads();
    const int buf = kt & 1;
    if (kt + 1 < 17) { preloadA(kt + 1); stageB(kt + 1, buf ^ 1); }
    compute(buf);
    if (kt + 1 < 17) writeA(buf ^ 1);
  }

  // epilogue: scatter into Wpk fragment layout; row 1056 -> cvec
#pragma unroll
  for (int m = 0; m < 4; ++m)
#pragma unroll
    for (int n = 0; n < 5; ++n) {
      if (n < nn) {
#pragma unroll
        for (int i = 0; i < 4; ++i) {
          const int row = mt * 128 + mg * 64 + m * 16 + (kq << 2) + i;
          const int col = (n0 + n) * 16 + l15;
          if (row < 1056) {
            const int ktw = row >> 5, kk = row & 31;
            const size_t off = (size_t)(p * 33 + ktw) * 4608 + (n0 + n) * 512 +
                               ((kk >> 3) * 16 + l15) * 8 + (kk & 7);
            Wpk[off] = f2bf(acc[m][n][i]);
          } else if (row == 1056) {
            cvec[p * 144 + col] = (col < 136) ? acc[m][n][i] + b1[p * 136 + col] : 0.f;
          }
        }
      }
    }
}

// ---------------- fused main kernel -----------------------------------------
__global__ __launch_bounds__(256, 2)
void k_main(const float* __restrict__ cell, const float* __restrict__ cond,
            const float* __restrict__ pe,
            const u16* __restrict__ Wpk, const u16* __restrict__ W2pk,
            const float* __restrict__ cvec, const float* __restrict__ b2,
            const float* __restrict__ W3, const float* __restrict__ b3,
            float* __restrict__ out) {
  __shared__ char smem[75776];
  char* const h1  = smem;            // 128 x 320B = 40960
  char* const Ab0 = smem + 40960;    // stage1 A dbuf: 2 x 8192
  char* const Bb0 = smem + 57344;    // stage1 B dbuf: 2 x 9216  (end 75776)
  char* const B2  = smem + 40960;    // stage2 B single buf: 17408 (aliases dead stage1)

  const int t = threadIdx.x, lane = t & 63, w = t >> 6;
  const int l15 = lane & 15, kq = lane >> 4;
  const int mg = w >> 1, ng = w & 1;
  const int n0 = ng * 5, nn = ng ? 4 : 5;

  // XCD-aware swizzle: each XCD owns 8 consecutive proteins (Wpk L2-resident)
  const unsigned lid = blockIdx.x;                   // 0..2047
  const int p  = ((lid & 7) << 3) | ((lid >> 8) & 7);
  const int b0 = ((lid >> 3) & 31) * 128;

  const int sr = t >> 1, sh = t & 1, sf = (sr >> 1) & 3;
  const long gr = b0 + sr;

  const f32x4 fz = {0.f, 0.f, 0.f, 0.f};
  f32x4 acc[4][5];
#pragma unroll
  for (int m = 0; m < 4; ++m)
#pragma unroll
    for (int n = 0; n < 5; ++n) acc[m][n] = fz;

  const u16* wsrc = Wpk + (size_t)p * (33 * 4608);

  float4 pv[4];
  auto preloadA = [&](int kt) {
    const float* s;
    if (kt < 16)      s = pe + ((gr * 64 + p) << 9) + kt * 32 + sh * 16;
    else if (kt < 32) s = cell + (gr << 9) + (kt - 16) * 32 + sh * 16;
    else              s = cond + (gr << 5) + sh * 16;
#pragma unroll
    for (int j = 0; j < 4; ++j) pv[j] = *(const float4*)(s + j * 4);
  };
  auto writeA = [&](int buf) {
    u16x8 v0, v1;
    v0[0] = f2bf(pv[0].x); v0[1] = f2bf(pv[0].y); v0[2] = f2bf(pv[0].z); v0[3] = f2bf(pv[0].w);
    v0[4] = f2bf(pv[1].x); v0[5] = f2bf(pv[1].y); v0[6] = f2bf(pv[1].z); v0[7] = f2bf(pv[1].w);
    v1[0] = f2bf(pv[2].x); v1[1] = f2bf(pv[2].y); v1[2] = f2bf(pv[2].z); v1[3] = f2bf(pv[2].w);
    v1[4] = f2bf(pv[3].x); v1[5] = f2bf(pv[3].y); v1[6] = f2bf(pv[3].z); v1[7] = f2bf(pv[3].w);
    char* dst = Ab0 + buf * 8192 + sr * 64;
    *(u16x8*)(dst + ((((sh << 1)) ^ sf) << 4)) = v0;
    *(u16x8*)(dst + ((((sh << 1) | 1) ^ sf) << 4)) = v1;
  };
  auto stageB = [&](int kt, int buf) {
    const u16* src = wsrc + kt * 4608;
    char* dst = Bb0 + buf * 9216;
    for (int i = w; i < 9; i += 4) gl_lds16(src + i * 512 + lane * 8, dst + i * 1024);
  };
  auto compute1 = [&](int buf) {
    const char* A = Ab0 + buf * 8192;
    const char* Bt = Bb0 + buf * 9216;
    bf16x8 a[4];
#pragma unroll
    for (int m = 0; m < 4; ++m) {
      const int row = mg * 64 + m * 16 + l15;
      a[m] = *(const bf16x8*)(A + row * 64 + ((kq ^ ((row >> 1) & 3)) << 4));
    }
#pragma unroll
    for (int n = 0; n < 5; ++n) {
      if (n < nn) {
        bf16x8 b = *(const bf16x8*)(Bt + (n0 + n) * 1024 + lane * 16);
#pragma unroll
        for (int m = 0; m < 4; ++m)
          acc[m][n] = __builtin_amdgcn_mfma_f32_16x16x32_bf16(a[m], b, acc[m][n], 0, 0, 0);
      }
    }
  };

  // ---- stage 1: h1_pre = [pe|cell|cond] @ Wcat_p  (K = 1056 = 33 x 32) ----
  preloadA(0); stageB(0, 0); writeA(0);
  for (int kt = 0; kt < 33; ++kt) {
    __syncthreads();
    const int buf = kt & 1;
    if (kt + 1 < 33) { preloadA(kt + 1); stageB(kt + 1, buf ^ 1); }
    compute1(buf);
    if (kt + 1 < 33) writeA(buf ^ 1);
  }
  __syncthreads();

  // ---- epilogue 1: +c_p, lrelu -> h1 (bf16, swizzled); zero K-pad ---------
  {
    const float* cp = cvec + p * 144;
#pragma unroll
    for (int m = 0; m < 4; ++m) {
      const int rb = mg * 64 + m * 16 + (kq << 2);
#pragma unroll
      for (int n = 0; n < 5; ++n) {
        if (n < nn) {
          const int col = (n0 + n) * 16 + l15;
          const float cb = cp[col];
#pragma unroll
          for (int i = 0; i < 4; ++i) {
            const int row = rb + i;
            float v = acc[m][n][i] + cb;
            v = v > 0.f ? v : 0.2f * v;
            const int u = (col >> 3) ^ ((row >> 1) & 3);
            *(u16*)(h1 + row * 320 + u * 16 + ((col & 7) << 1)) = f2bf(v);
          }
        }
      }
    }
    const int uz = (18 + sh) ^ sf;       // zero cols 144..159
    u16x8 z = {0, 0, 0, 0, 0, 0, 0, 0};
    *(u16x8*)(h1 + sr * 320 + uz * 16) = z;
  }
  __syncthreads();   // h1 complete before stage 2

  // ---- stage 2: h2 = lrelu(h1 @ W2_p + b2)  (K=160 = 5x32, N=272) ---------
  // single-buffer, two barriers per iteration (r2-proven schedule)
  f32x4 acc2[2][17];
#pragma unroll
  for (int m = 0; m < 2; ++m)
#pragma unroll
    for (int n = 0; n < 17; ++n) acc2[m][n] = fz;

  const u16* w2src = W2pk + (size_t)p * (5 * 8704);
  for (int kt = 0; kt < 5; ++kt) {
    for (int i = w; i < 17; i += 4)
      gl_lds16(w2src + kt * 8704 + i * 512 + lane * 8, B2 + i * 1024);
    __syncthreads();     // staging landed (vmcnt drained before barrier)
    bf16x8 a[2];
#pragma unroll
    for (int m = 0; m < 2; ++m) {
      const int row = w * 32 + m * 16 + l15;
      const int u = (kt * 4 + kq) ^ ((row >> 1) & 3);
      a[m] = *(const bf16x8*)(h1 + row * 320 + u * 16);
    }
#pragma unroll
    for (int n = 0; n < 17; ++n) {
      bf16x8 b = *(const bf16x8*)(B2 + n * 1024 + lane * 16);
      acc2[0][n] = __builtin_amdgcn_mfma_f32_16x16x32_bf16(a[0], b, acc2[0][n], 0, 0, 0);
      acc2[1][n] = __builtin_amdgcn_mfma_f32_16x16x32_bf16(a[1], b, acc2[1][n], 0, 0, 0);
    }
    __syncthreads();     // all reads done before next iteration overwrites B2
  }

  // ---- stage 3: out = lrelu(h2) . w3 + b3 (in-register + shfl reduce) -----
  {
    const float* w3p = W3 + p * 272;
    const float* b2p = b2 + p * 272;
    const float b3v = b3[p];
    float w3v[17], b2v[17];
#pragma unroll
    for (int n = 0; n < 17; ++n) { w3v[n] = w3p[n * 16 + l15]; b2v[n] = b2p[n * 16 + l15]; }
#pragma unroll
    for (int m = 0; m < 2; ++m) {
#pragma unroll
      for (int i = 0; i < 4; ++i) {
        float s = 0.f;
#pragma unroll
        for (int n = 0; n < 17; ++n) {
          float h = acc2[m][n][i] + b2v[n];
          h = h > 0.f ? h : 0.2f * h;
          s += h * w3v[n];
        }
        s += __shfl_xor(s, 1);
        s += __shfl_xor(s, 2);
        s += __shfl_xor(s, 4);
        s += __shfl_xor(s, 8);
        if (l15 == 0) {
          const int row = w * 32 + m * 16 + (kq << 2) + i;
          out[(size_t)(b0 + row) * 64 + p] = s + b3v;
        }
      }
    }
  }
}

// ---------------------------------------------------------------------------
extern "C" void kernel_launch(void* const* d_in, const int* in_sizes, int n_in,
                              void* d_out, int out_size, void* d_ws, size_t ws_size,
                              hipStream_t stream) {
  const float* cell   = (const float*)d_in[0];   // [4096,512]
  const float* cond   = (const float*)d_in[1];   // [4096,32]
  const float* pe     = (const float*)d_in[2];   // [4096,64,512]
  const float* projW  = (const float*)d_in[3];   // [512,512]
  const float* projb  = (const float*)d_in[4];   // [512]
  const float* transW = (const float*)d_in[5];   // [1056,544]
  const float* transb = (const float*)d_in[6];   // [544]
  const float* W1     = (const float*)d_in[7];   // [64,544,136]
  const float* b1     = (const float*)d_in[8];   // [64,136]
  const float* W2     = (const float*)d_in[9];   // [64,136,272]
  const float* b2     = (const float*)d_in[10];  // [64,272]
  const float* W3     = (const float*)d_in[11];  // [64,272,1]
  const float* b3     = (const float*)d_in[12];  // [64,1]
  float* out = (float*)d_out;

  char* ws = (char*)d_ws;
  float* G    = (float*)(ws);                    // 1152*544*4   = 2,506,752
  u16*  W1pk  = (u16*)(ws + 2506752);            // 64*17*9216   = 10,027,008
  u16*  Wpk   = (u16*)(ws + 12533760);           // 64*33*9216   = 19,464,192
  u16*  W2pk  = (u16*)(ws + 31997952);           // 64*5*17408   = 5,570,560
  float* cvec = (float*)(ws + 37568512);         // 64*144*4     (end 37,605,376)

  k_pre <<<4199, 256, 0, stream>>>(projW, transW, projb, transb, W1, W2, G, W1pk, W2pk);
  k_pk3 <<<dim3(9, 64), 256, 0, stream>>>(G, W1pk, b1, Wpk, cvec);
  k_main<<<2048, 256, 0, stream>>>(cell, cond, pe, Wpk, W2pk, cvec, b2, W3, b3, out);
}

// Round 5
// 310.452 us; speedup vs baseline: 3.0156x; 1.0513x over previous
//
#include <hip/hip_runtime.h>

// ---------------------------------------------------------------------------
// PredictModelWithCLasses: fused per-protein MLP on MI355X (gfx950).
//
// out[b,p] = w3_p . lrelu( W2_p^T . lrelu( Wcat_p^T . [pe(b,p)|spot(b)] + c_p ) + b2_p ) + b3_p
// Wcat_p = [proj_W @ TW_top ; TW_bot] @ W1_p  (1056x136) — fusable since there
// is no activation between trans_dim and W1.
//
// Round 5 (vs r4, which passed at 326us):
//  - ALL f32->bf16 conversion via v_cvt_pk_bf16_f32 (1 inst / 2 elems, RTNE)
//    instead of 4-op bit-twiddle ("repack-bound" fix; no sync changes)
//  - lrelu as fmax(x, 0.2x) (branchless, 2 VALU)
//  - k_pk3 epilogue: per-quad u16 stores merged into one uint2 store
// ---------------------------------------------------------------------------

typedef short bf16x8 __attribute__((ext_vector_type(8)));   // 8 bf16 (raw bits)
typedef unsigned short u16;
typedef u16 u16x8 __attribute__((ext_vector_type(8)));
typedef unsigned u32x4 __attribute__((ext_vector_type(4)));
typedef float f32x4 __attribute__((ext_vector_type(4)));

typedef const void __attribute__((address_space(1)))* gas_p;
typedef void __attribute__((address_space(3)))* las_p;

__device__ __forceinline__ void gl_lds16(const void* g, void* l) {
  __builtin_amdgcn_global_load_lds((gas_p)g, (las_p)l, 16, 0, 0);
}

__device__ __forceinline__ unsigned cvtpk(float lo, float hi) {
  // dst = bf16(hi)<<16 | bf16(lo), RTNE
  unsigned r;
  asm("v_cvt_pk_bf16_f32 %0, %1, %2" : "=v"(r) : "v"(lo), "v"(hi));
  return r;
}

__device__ __forceinline__ u16 f2bf(float f) {  // scalar fallback (rare paths)
  union { float f; unsigned u; } x; x.f = f;
  return (u16)((x.u + 0x7FFFu + ((x.u >> 16) & 1u)) >> 16);
}

__device__ __forceinline__ float lrelu(float x) { return fmaxf(x, 0.2f * x); }

// ---------------- fused precompute (block-range dispatch) -------------------
// blocks [0,72): G top = projW @ TW_top (64x64 tile f32 GEMM)
// blocks [72,361): G rows 512..1055 = copy TW_bot
// blocks [361,378): G row 1056 = proj_b @ TW_top + trans_b
// blocks [378,391): G rows 1057..1151 = 0
// blocks [391,2839): pack W1 -> MFMA-B bf16 fragments
// blocks [2839,4199): pack W2 -> MFMA-B bf16 fragments (K pad 136->160)
__global__ __launch_bounds__(256)
void k_pre(const float* __restrict__ projW, const float* __restrict__ transW,
           const float* __restrict__ projb, const float* __restrict__ transb,
           const float* __restrict__ W1, const float* __restrict__ W2,
           float* __restrict__ G, u16* __restrict__ W1pk, u16* __restrict__ W2pk) {
  __shared__ float As[16][68];
  __shared__ float Bs[16][68];
  const int bb = blockIdx.x, t = threadIdx.x;

  if (bb < 72) {                       // ---- G top GEMM ----
    const int m0 = (bb & 7) * 64, c0 = (bb >> 3) * 64;
    const int tx = t & 15, ty = t >> 4;
    const int ar = t >> 2, akk = (t & 3) * 4;
    const int bkk = t >> 4, bcc = (t & 15) * 4;
    const bool bok = (c0 + bcc) < 544;
    float acc[4][4];
#pragma unroll
    for (int i = 0; i < 4; ++i)
#pragma unroll
      for (int j = 0; j < 4; ++j) acc[i][j] = 0.f;
    for (int k0 = 0; k0 < 512; k0 += 16) {
      const float4 av = *(const float4*)(projW + (size_t)(m0 + ar) * 512 + k0 + akk);
      float4 bv = {0.f, 0.f, 0.f, 0.f};
      if (bok) bv = *(const float4*)(transW + (size_t)(k0 + bkk) * 544 + c0 + bcc);
      __syncthreads();
      As[akk + 0][ar] = av.x; As[akk + 1][ar] = av.y;
      As[akk + 2][ar] = av.z; As[akk + 3][ar] = av.w;
      *(float4*)&Bs[bkk][bcc] = bv;
      __syncthreads();
#pragma unroll
      for (int kk = 0; kk < 16; ++kk) {
        const float4 a = *(const float4*)&As[kk][ty * 4];
        const float4 b = *(const float4*)&Bs[kk][tx * 4];
        const float aa[4] = {a.x, a.y, a.z, a.w};
        const float bb2[4] = {b.x, b.y, b.z, b.w};
#pragma unroll
        for (int i = 0; i < 4; ++i)
#pragma unroll
          for (int j = 0; j < 4; ++j) acc[i][j] += aa[i] * bb2[j];
      }
    }
    if ((c0 + tx * 4) < 544) {
#pragma unroll
      for (int i = 0; i < 4; ++i) {
        float4 v = {acc[i][0], acc[i][1], acc[i][2], acc[i][3]};
        *(float4*)(G + (size_t)(m0 + ty * 4 + i) * 544 + c0 + tx * 4) = v;
      }
    }
  } else if (bb < 361) {               // ---- G rows 512..1055 copy ----
    const int idx = (bb - 72) * 256 + t;
    if (idx < 73984) ((float4*)G)[69632 + idx] = ((const float4*)transW)[69632 + idx];
  } else if (bb < 378) {               // ---- G row 1056 = d-vector ----
    __shared__ float red[256];
    const int c = (bb - 361) * 32 + (t & 31);
    const int kp = t >> 5;
    float s = 0.f;
    for (int k = kp * 64; k < kp * 64 + 64; ++k) s += projb[k] * transW[(size_t)k * 544 + c];
    red[t] = s;
    __syncthreads();
    if (t < 32) {
      float v = red[t];
#pragma unroll
      for (int j = 1; j < 8; ++j) v += red[t + 32 * j];
      const int cc = (bb - 361) * 32 + t;
      G[(size_t)1056 * 544 + cc] = v + transb[cc];
    }
  } else if (bb < 391) {               // ---- G rows 1057..1151 = 0 ----
    const int idx = (bb - 378) * 256 + t;
    const float4 z = {0.f, 0.f, 0.f, 0.f};
#pragma unroll
    for (int j = 0; j < 4; ++j) {
      const int k = idx + j * 3328;
      if (k < 12920) ((float4*)G)[143752 + k] = z;
    }
  } else if (bb < 2839) {              // ---- pack W1 ----
    const int uid = (bb - 391) * 256 + t;           // < 626688
    const int unit = uid & 63;
    const int rest = uid >> 6;
    const int n = rest % 9;
    const int tile = rest / 9;
    const int kt = tile % 17;
    const int pp = tile / 17;
    const int kb = unit >> 4, cl = unit & 15;
    const int colg = n * 16 + cl;
    float f[8];
#pragma unroll
    for (int j = 0; j < 8; ++j) {
      const int k = kt * 32 + kb * 8 + j;
      f[j] = (colg < 136) ? W1[((size_t)pp * 544 + k) * 136 + colg] : 0.f;
    }
    u32x4 v = {cvtpk(f[0], f[1]), cvtpk(f[2], f[3]), cvtpk(f[4], f[5]), cvtpk(f[6], f[7])};
    *(u32x4*)(W1pk + (size_t)uid * 8) = v;
  } else {                             // ---- pack W2 ----
    const int uid = (bb - 2839) * 256 + t;          // < 348160
    const int unit = uid & 63;
    const int rest = uid >> 6;
    const int n = rest % 17;
    const int tile = rest / 17;
    const int kt = tile % 5;
    const int pp = tile / 5;
    const int kb = unit >> 4, cl = unit & 15;
    const int colg = n * 16 + cl;
    float f[8];
#pragma unroll
    for (int j = 0; j < 8; ++j) {
      const int k = kt * 32 + kb * 8 + j;
      f[j] = (k < 136) ? W2[((size_t)pp * 136 + k) * 272 + colg] : 0.f;
    }
    u32x4 v = {cvtpk(f[0], f[1]), cvtpk(f[2], f[3]), cvtpk(f[4], f[5]), cvtpk(f[6], f[7])};
    *(u32x4*)(W2pk + (size_t)uid * 8) = v;
  }
}

// ---------------- grouped GEMM: Wcat_p = G @ W1_p ---------------------------
// M=1152 (9x128, rows>=1057 are zeros/discard), K=544 (17 steps), N=144.
// Row 1056 of the product = c_p - b1_p -> written to cvec (+b1, pad 0).
__global__ __launch_bounds__(256, 2)
void k_pk3(const float* __restrict__ G, const u16* __restrict__ W1pk,
           const float* __restrict__ b1, u16* __restrict__ Wpk,
           float* __restrict__ cvec) {
  __shared__ char smem[34816];
  char* const Ab0 = smem;            // 2 x 8192
  char* const Bb0 = smem + 16384;    // 2 x 9216
  const int t = threadIdx.x, lane = t & 63, w = t >> 6;
  const int l15 = lane & 15, kq = lane >> 4;
  const int mg = w >> 1, ng = w & 1;
  const int n0 = ng * 5, nn = ng ? 4 : 5;
  const int mt = blockIdx.x, p = blockIdx.y;
  const int sr = t >> 1, sh = t & 1, sf = (sr >> 1) & 3;
  const int gr = mt * 128 + sr;

  const f32x4 fz = {0.f, 0.f, 0.f, 0.f};
  f32x4 acc[4][5];
#pragma unroll
  for (int m = 0; m < 4; ++m)
#pragma unroll
    for (int n = 0; n < 5; ++n) acc[m][n] = fz;

  const u16* wsrc = W1pk + (size_t)p * (17 * 4608);

  float4 pv[4];
  auto preloadA = [&](int kt) {
    const float* s = G + (size_t)gr * 544 + kt * 32 + sh * 16;
#pragma unroll
    for (int j = 0; j < 4; ++j) pv[j] = *(const float4*)(s + j * 4);
  };
  auto writeA = [&](int buf) {
    u32x4 v0 = {cvtpk(pv[0].x, pv[0].y), cvtpk(pv[0].z, pv[0].w),
                cvtpk(pv[1].x, pv[1].y), cvtpk(pv[1].z, pv[1].w)};
    u32x4 v1 = {cvtpk(pv[2].x, pv[2].y), cvtpk(pv[2].z, pv[2].w),
                cvtpk(pv[3].x, pv[3].y), cvtpk(pv[3].z, pv[3].w)};
    char* dst = Ab0 + buf * 8192 + sr * 64;
    *(u32x4*)(dst + ((((sh << 1)) ^ sf) << 4)) = v0;
    *(u32x4*)(dst + ((((sh << 1) | 1) ^ sf) << 4)) = v1;
  };
  auto stageB = [&](int kt, int buf) {
    const u16* src = wsrc + kt * 4608;
    char* dst = Bb0 + buf * 9216;
    for (int i = w; i < 9; i += 4) gl_lds16(src + i * 512 + lane * 8, dst + i * 1024);
  };
  auto compute = [&](int buf) {
    const char* A = Ab0 + buf * 8192;
    const char* Bt = Bb0 + buf * 9216;
    bf16x8 a[4];
#pragma unroll
    for (int m = 0; m < 4; ++m) {
      const int row = mg * 64 + m * 16 + l15;
      a[m] = *(const bf16x8*)(A + row * 64 + ((kq ^ ((row >> 1) & 3)) << 4));
    }
#pragma unroll
    for (int n = 0; n < 5; ++n) {
      if (n < nn) {
        bf16x8 b = *(const bf16x8*)(Bt + (n0 + n) * 1024 + lane * 16);
#pragma unroll
        for (int m = 0; m < 4; ++m)
          acc[m][n] = __builtin_amdgcn_mfma_f32_16x16x32_bf16(a[m], b, acc[m][n], 0, 0, 0);
      }
    }
  };

  preloadA(0); stageB(0, 0); writeA(0);
  for (int kt = 0; kt < 17; ++kt) {
    __syncthreads();
    const int buf = kt & 1;
    if (kt + 1 < 17) { preloadA(kt + 1); stageB(kt + 1, buf ^ 1); }
    compute(buf);
    if (kt + 1 < 17) writeA(buf ^ 1);
  }

  // epilogue: scatter into Wpk fragment layout; row 1056 -> cvec.
  // The 4 accs of a quad go to CONSECUTIVE u16 slots -> one uint2 store.
#pragma unroll
  for (int m = 0; m < 4; ++m)
#pragma unroll
    for (int n = 0; n < 5; ++n) {
      if (n < nn) {
        const int row0 = mt * 128 + mg * 64 + m * 16 + (kq << 2);  // quad-aligned
        const int col = (n0 + n) * 16 + l15;
        if (row0 < 1056) {
          const int ktw = row0 >> 5, kk = row0 & 31;
          const size_t off = (size_t)(p * 33 + ktw) * 4608 + (n0 + n) * 512 +
                             ((kk >> 3) * 16 + l15) * 8 + (kk & 7);
          uint2 pk = {cvtpk(acc[m][n][0], acc[m][n][1]),
                      cvtpk(acc[m][n][2], acc[m][n][3])};
          *(uint2*)(Wpk + off) = pk;
        } else if (row0 == 1056) {
          cvec[p * 144 + col] = (col < 136) ? acc[m][n][0] + b1[p * 136 + col] : 0.f;
        }
      }
    }
}

// ---------------- fused main kernel -----------------------------------------
__global__ __launch_bounds__(256, 2)
void k_main(const float* __restrict__ cell, const float* __restrict__ cond,
            const float* __restrict__ pe,
            const u16* __restrict__ Wpk, const u16* __restrict__ W2pk,
            const float* __restrict__ cvec, const float* __restrict__ b2,
            const float* __restrict__ W3, const float* __restrict__ b3,
            float* __restrict__ out) {
  __shared__ char smem[75776];
  char* const h1  = smem;            // 128 x 320B = 40960
  char* const Ab0 = smem + 40960;    // stage1 A dbuf: 2 x 8192
  char* const Bb0 = smem + 57344;    // stage1 B dbuf: 2 x 9216  (end 75776)
  char* const B2  = smem + 40960;    // stage2 B single buf: 17408 (aliases dead stage1)

  const int t = threadIdx.x, lane = t & 63, w = t >> 6;
  const int l15 = lane & 15, kq = lane >> 4;
  const int mg = w >> 1, ng = w & 1;
  const int n0 = ng * 5, nn = ng ? 4 : 5;

  // XCD-aware swizzle: each XCD owns 8 consecutive proteins (Wpk L2-resident)
  const unsigned lid = blockIdx.x;                   // 0..2047
  const int p  = ((lid & 7) << 3) | ((lid >> 8) & 7);
  const int b0 = ((lid >> 3) & 31) * 128;

  const int sr = t >> 1, sh = t & 1, sf = (sr >> 1) & 3;
  const long gr = b0 + sr;

  const f32x4 fz = {0.f, 0.f, 0.f, 0.f};
  f32x4 acc[4][5];
#pragma unroll
  for (int m = 0; m < 4; ++m)
#pragma unroll
    for (int n = 0; n < 5; ++n) acc[m][n] = fz;

  const u16* wsrc = Wpk + (size_t)p * (33 * 4608);

  float4 pv[4];
  auto preloadA = [&](int kt) {
    const float* s;
    if (kt < 16)      s = pe + ((gr * 64 + p) << 9) + kt * 32 + sh * 16;
    else if (kt < 32) s = cell + (gr << 9) + (kt - 16) * 32 + sh * 16;
    else              s = cond + (gr << 5) + sh * 16;
#pragma unroll
    for (int j = 0; j < 4; ++j) pv[j] = *(const float4*)(s + j * 4);
  };
  auto writeA = [&](int buf) {
    u32x4 v0 = {cvtpk(pv[0].x, pv[0].y), cvtpk(pv[0].z, pv[0].w),
                cvtpk(pv[1].x, pv[1].y), cvtpk(pv[1].z, pv[1].w)};
    u32x4 v1 = {cvtpk(pv[2].x, pv[2].y), cvtpk(pv[2].z, pv[2].w),
                cvtpk(pv[3].x, pv[3].y), cvtpk(pv[3].z, pv[3].w)};
    char* dst = Ab0 + buf * 8192 + sr * 64;
    *(u32x4*)(dst + ((((sh << 1)) ^ sf) << 4)) = v0;
    *(u32x4*)(dst + ((((sh << 1) | 1) ^ sf) << 4)) = v1;
  };
  auto stageB = [&](int kt, int buf) {
    const u16* src = wsrc + kt * 4608;
    char* dst = Bb0 + buf * 9216;
    for (int i = w; i < 9; i += 4) gl_lds16(src + i * 512 + lane * 8, dst + i * 1024);
  };
  auto compute1 = [&](int buf) {
    const char* A = Ab0 + buf * 8192;
    const char* Bt = Bb0 + buf * 9216;
    bf16x8 a[4];
#pragma unroll
    for (int m = 0; m < 4; ++m) {
      const int row = mg * 64 + m * 16 + l15;
      a[m] = *(const bf16x8*)(A + row * 64 + ((kq ^ ((row >> 1) & 3)) << 4));
    }
#pragma unroll
    for (int n = 0; n < 5; ++n) {
      if (n < nn) {
        bf16x8 b = *(const bf16x8*)(Bt + (n0 + n) * 1024 + lane * 16);
#pragma unroll
        for (int m = 0; m < 4; ++m)
          acc[m][n] = __builtin_amdgcn_mfma_f32_16x16x32_bf16(a[m], b, acc[m][n], 0, 0, 0);
      }
    }
  };

  // ---- stage 1: h1_pre = [pe|cell|cond] @ Wcat_p  (K = 1056 = 33 x 32) ----
  preloadA(0); stageB(0, 0); writeA(0);
  for (int kt = 0; kt < 33; ++kt) {
    __syncthreads();
    const int buf = kt & 1;
    if (kt + 1 < 33) { preloadA(kt + 1); stageB(kt + 1, buf ^ 1); }
    compute1(buf);
    if (kt + 1 < 33) writeA(buf ^ 1);
  }
  __syncthreads();

  // ---- epilogue 1: +c_p, lrelu -> h1 (bf16, swizzled); zero K-pad ---------
  {
    const float* cp = cvec + p * 144;
#pragma unroll
    for (int m = 0; m < 4; ++m) {
      const int rb = mg * 64 + m * 16 + (kq << 2);
#pragma unroll
      for (int n = 0; n < 5; ++n) {
        if (n < nn) {
          const int col = (n0 + n) * 16 + l15;
          const float cb = cp[col];
#pragma unroll
          for (int i = 0; i < 4; i += 2) {     // row pairs share the swizzle u
            const int row = rb + i;
            const float va = lrelu(acc[m][n][i] + cb);
            const float vb = lrelu(acc[m][n][i + 1] + cb);
            const unsigned pk = cvtpk(va, vb);
            const int u = (col >> 3) ^ ((row >> 1) & 3);
            char* a0 = h1 + row * 320 + u * 16 + ((col & 7) << 1);
            *(u16*)a0 = (u16)pk;
            *(u16*)(a0 + 320) = (u16)(pk >> 16);
          }
        }
      }
    }
    const int uz = (18 + sh) ^ sf;       // zero cols 144..159
    u16x8 z = {0, 0, 0, 0, 0, 0, 0, 0};
    *(u16x8*)(h1 + sr * 320 + uz * 16) = z;
  }
  __syncthreads();   // h1 complete before stage 2

  // ---- stage 2: h2 = lrelu(h1 @ W2_p + b2)  (K=160 = 5x32, N=272) ---------
  // single-buffer, two barriers per iteration (r2-proven schedule)
  f32x4 acc2[2][17];
#pragma unroll
  for (int m = 0; m < 2; ++m)
#pragma unroll
    for (int n = 0; n < 17; ++n) acc2[m][n] = fz;

  const u16* w2src = W2pk + (size_t)p * (5 * 8704);
  for (int kt = 0; kt < 5; ++kt) {
    for (int i = w; i < 17; i += 4)
      gl_lds16(w2src + kt * 8704 + i * 512 + lane * 8, B2 + i * 1024);
    __syncthreads();     // staging landed (vmcnt drained before barrier)
    bf16x8 a[2];
#pragma unroll
    for (int m = 0; m < 2; ++m) {
      const int row = w * 32 + m * 16 + l15;
      const int u = (kt * 4 + kq) ^ ((row >> 1) & 3);
      a[m] = *(const bf16x8*)(h1 + row * 320 + u * 16);
    }
#pragma unroll
    for (int n = 0; n < 17; ++n) {
      bf16x8 b = *(const bf16x8*)(B2 + n * 1024 + lane * 16);
      acc2[0][n] = __builtin_amdgcn_mfma_f32_16x16x32_bf16(a[0], b, acc2[0][n], 0, 0, 0);
      acc2[1][n] = __builtin_amdgcn_mfma_f32_16x16x32_bf16(a[1], b, acc2[1][n], 0, 0, 0);
    }
    __syncthreads();     // all reads done before next iteration overwrites B2
  }

  // ---- stage 3: out = lrelu(h2) . w3 + b3 (in-register + shfl reduce) -----
  {
    const float* w3p = W3 + p * 272;
    const float* b2p = b2 + p * 272;
    const float b3v = b3[p];
    float w3v[17], b2v[17];
#pragma unroll
    for (int n = 0; n < 17; ++n) { w3v[n] = w3p[n * 16 + l15]; b2v[n] = b2p[n * 16 + l15]; }
#pragma unroll
    for (int m = 0; m < 2; ++m) {
#pragma unroll
      for (int i = 0; i < 4; ++i) {
        float s = 0.f;
#pragma unroll
        for (int n = 0; n < 17; ++n) {
          const float h = lrelu(acc2[m][n][i] + b2v[n]);
          s += h * w3v[n];
        }
        s += __shfl_xor(s, 1);
        s += __shfl_xor(s, 2);
        s += __shfl_xor(s, 4);
        s += __shfl_xor(s, 8);
        if (l15 == 0) {
          const int row = w * 32 + m * 16 + (kq << 2) + i;
          out[(size_t)(b0 + row) * 64 + p] = s + b3v;
        }
      }
    }
  }
}

// ---------------------------------------------------------------------------
extern "C" void kernel_launch(void* const* d_in, const int* in_sizes, int n_in,
                              void* d_out, int out_size, void* d_ws, size_t ws_size,
                              hipStream_t stream) {
  const float* cell   = (const float*)d_in[0];   // [4096,512]
  const float* cond   = (const float*)d_in[1];   // [4096,32]
  const float* pe     = (const float*)d_in[2];   // [4096,64,512]
  const float* projW  = (const float*)d_in[3];   // [512,512]
  const float* projb  = (const float*)d_in[4];   // [512]
  const float* transW = (const float*)d_in[5];   // [1056,544]
  const float* transb = (const float*)d_in[6];   // [544]
  const float* W1     = (const float*)d_in[7];   // [64,544,136]
  const float* b1     = (const float*)d_in[8];   // [64,136]
  const float* W2     = (const float*)d_in[9];   // [64,136,272]
  const float* b2     = (const float*)d_in[10];  // [64,272]
  const float* W3     = (const float*)d_in[11];  // [64,272,1]
  const float* b3     = (const float*)d_in[12];  // [64,1]
  float* out = (float*)d_out;

  char* ws = (char*)d_ws;
  float* G    = (float*)(ws);                    // 1152*544*4   = 2,506,752
  u16*  W1pk  = (u16*)(ws + 2506752);            // 64*17*9216   = 10,027,008
  u16*  Wpk   = (u16*)(ws + 12533760);           // 64*33*9216   = 19,464,192
  u16*  W2pk  = (u16*)(ws + 31997952);           // 64*5*17408   = 5,570,560
  float* cvec = (float*)(ws + 37568512);         // 64*144*4     (end 37,605,376)

  k_pre <<<4199, 256, 0, stream>>>(projW, transW, projb, transb, W1, W2, G, W1pk, W2pk);
  k_pk3 <<<dim3(9, 64), 256, 0, stream>>>(G, W1pk, b1, Wpk, cvec);
  k_main<<<2048, 256, 0, stream>>>(cell, cond, pe, Wpk, W2pk, cvec, b2, W3, b3, out);
}